// Round 9
// baseline (81.419 us; speedup 1.0000x reference)
//
#include <hip/hip_runtime.h>

#define B_SZ 256
#define D_SZ 256
#define M_SZ 65536
#define C_SZ 1000
#define TEMP 0.05f
#define EPSF 1e-6f

#define NBLK 256
#define NBLK_SORT 32
#define CHUNK (M_SZ / NBLK_SORT)   // 2048 labels per sort block

// ---- ws layout (bytes) ----
#define OFF_FCT    0          // float[D_SZ*C_SZ] = 1,024,000 B (transposed, pre-scaled)
#define OFF_NUMS   1024000    // int[C_SZ]
#define OFF_OFFS   1028000    // int[C_SZ]
#define OFF_CTRL   1032000    // int bar1,bar2,bar3,lcnt; float acc[2]  (24 B, memset each call)
#define OFF_COUNTS 1032064    // int[NBLK_SORT*C_SZ] = 128,000 B
#define OFF_MEMB   1160064    // int[M_SZ] = 262,144 B

// Lean device barrier halves.
// Release: __syncthreads (compiler emits full waitcnt before s_barrier, so all
// block stores are in L2) + ONE agent-scope release atomic per block (emits a
// single buffer_wbl2 to flush this XCD's dirty L2 lines). NOT per-thread
// threadfence — that was R5's 150µs fence storm.
__device__ __forceinline__ void bar_add(int* b) {
    __syncthreads();
    if (threadIdx.x == 0)
        __hip_atomic_fetch_add(b, 1, __ATOMIC_RELEASE, __HIP_MEMORY_SCOPE_AGENT);
}
// Wait: relaxed polls (no cache ops while spinning) + one acquire load on exit
// (cache-wide L1/L2 invalidate), then block-local barrier.
__device__ __forceinline__ void bar_wait(int* b, int target) {
    if (threadIdx.x == 0) {
        while (__hip_atomic_load(b, __ATOMIC_RELAXED, __HIP_MEMORY_SCOPE_AGENT) < target)
            __builtin_amdgcn_s_sleep(8);
        int v = __hip_atomic_load(b, __ATOMIC_ACQUIRE, __HIP_MEMORY_SCOPE_AGENT);
        asm volatile("" :: "v"(v));   // keep the acquire load live
    }
    __syncthreads();
}

__launch_bounds__(1024)
__global__ void k_all(const float* __restrict__ features,
                      const int* __restrict__ labels,
                      const float* __restrict__ feat,
                      const float* __restrict__ soft,
                      const int* __restrict__ indexes,
                      const int* __restrict__ bil,
                      const int* __restrict__ cur_epoch,
                      float* __restrict__ fct, int* __restrict__ nums,
                      int* __restrict__ offs, int* __restrict__ counts,
                      int* __restrict__ members, int* __restrict__ ctrl,
                      float* __restrict__ out) {
    int* bar1 = &ctrl[0];
    int* bar2 = &ctrl[1];
    int* bar3 = &ctrl[2];
    int* lcnt = &ctrl[3];
    float* acc = (float*)&ctrl[4];

    __shared__ int h[C_SZ];
    __shared__ int sc[1024];
    __shared__ float xs0[D_SZ], xs1[D_SZ];
    __shared__ float wred[16], wred2[16];
    __shared__ float bc0, bc1;
    __shared__ int tgt0, tgt1, sr0, sr1;

    int t = threadIdx.x, bid = blockIdx.x;

    if (bid < NBLK_SORT) {
        // ---- phase 1: per-chunk LDS histogram ----
        if (t < C_SZ) h[t] = 0;
        __syncthreads();
        int start = bid * CHUNK;
        #pragma unroll
        for (int k = 0; k < CHUNK / 1024; ++k)
            atomicAdd(&h[labels[start + k * 1024 + t]], 1);  // LDS atomic
        __syncthreads();
        if (t < C_SZ) counts[bid * C_SZ + t] = h[t];

        bar_add(bar1);
        bar_wait(bar1, NBLK_SORT);

        // ---- phase 2: scatter (redundant parallel scan) ----
        int tot = 0, mybase = 0;
        if (t < C_SZ) {
            #pragma unroll
            for (int bb = 0; bb < NBLK_SORT; ++bb) {
                int v = counts[bb * C_SZ + t];
                tot += v;
                if (bb < bid) mybase += v;
            }
        }
        sc[t] = tot;
        __syncthreads();
        for (int d = 1; d < 1024; d <<= 1) {
            int v = (t >= d) ? sc[t - d] : 0;
            __syncthreads();
            sc[t] += v;
            __syncthreads();
        }
        if (t < C_SZ) {
            int e = sc[t] - tot;
            h[t] = e + mybase;  // reuse h as this block's write cursor
            if (bid == 0) { nums[t] = tot; offs[t] = e; }
        }
        __syncthreads();
        #pragma unroll
        for (int k = 0; k < CHUNK / 1024; ++k) {
            int m = start + k * 1024 + t;
            int pos = atomicAdd(&h[labels[m]], 1);  // LDS atomic
            members[pos] = m;
        }
        bar_add(bar2);
    }

    // everyone waits for the sort to finish
    bar_wait(bar2, NBLK_SORT);

    // ---- phase 3: classsum, class c = bid*4 + (t>>8), dim tt = t&255 ----
    {
        int g = t >> 8, tt = t & 255;
        int c = bid * 4 + g;
        if (c < C_SZ) {
            int beg = offs[c], n = nums[c];
            float a0 = 0.f, a1 = 0.f, a2 = 0.f, a3 = 0.f;
            float a4 = 0.f, a5 = 0.f, a6 = 0.f, a7 = 0.f;
            int i = 0;
            for (; i + 8 <= n; i += 8) {
                int r0 = members[beg + i + 0];
                int r1 = members[beg + i + 1];
                int r2 = members[beg + i + 2];
                int r3 = members[beg + i + 3];
                int r4 = members[beg + i + 4];
                int r5 = members[beg + i + 5];
                int r6 = members[beg + i + 6];
                int r7 = members[beg + i + 7];
                a0 += features[(size_t)r0 * D_SZ + tt];
                a1 += features[(size_t)r1 * D_SZ + tt];
                a2 += features[(size_t)r2 * D_SZ + tt];
                a3 += features[(size_t)r3 * D_SZ + tt];
                a4 += features[(size_t)r4 * D_SZ + tt];
                a5 += features[(size_t)r5 * D_SZ + tt];
                a6 += features[(size_t)r6 * D_SZ + tt];
                a7 += features[(size_t)r7 * D_SZ + tt];
            }
            for (; i < n; ++i) a0 += features[(size_t)members[beg + i] * D_SZ + tt];
            float s = ((a0 + a1) + (a2 + a3)) + ((a4 + a5) + (a6 + a7));
            float scale = 1.0f / (TEMP * (float)(n > 0 ? n : 1));
            fct[(size_t)tt * C_SZ + c] = s * scale;
        }
    }
    bar_add(bar3);

    if (bid >= B_SZ / 2) return;   // blocks 128-255: release-only, no spin

    bar_wait(bar3, NBLK);

    // ---- phase 4: loss for rows 2*bid, 2*bid+1 (R7's proven body) ----
    int lane = t & 63, wid = t >> 6;
    int r0 = bid * 2;

    if (t == 0) {
        tgt0 = labels[indexes[r0]];
        tgt1 = labels[indexes[r0 + 1]];
        sr0 = bil[r0];
        sr1 = bil[r0 + 1];
    }

    float v = (t < 512) ? feat[(size_t)r0 * D_SZ + t] : 0.f;
    float s = v * v;
    #pragma unroll
    for (int o = 32; o; o >>= 1) s += __shfl_down(s, o);
    if (lane == 0) wred[wid] = s;  // waves 0-3 = row0, 4-7 = row1
    __syncthreads();
    if (t == 0) {
        bc0 = fmaxf(sqrtf(wred[0] + wred[1] + wred[2] + wred[3]), 1e-12f);
        bc1 = fmaxf(sqrtf(wred[4] + wred[5] + wred[6] + wred[7]), 1e-12f);
    }
    __syncthreads();
    if (t < 256) xs0[t] = v / bc0;
    else if (t < 512) xs1[t - 256] = v / bc1;
    __syncthreads();

    float a0 = 0.f, a1 = 0.f;
    if (t < C_SZ) {
        #pragma unroll 8
        for (int i = 0; i < D_SZ; ++i) {
            float f = fct[(size_t)i * C_SZ + t];  // coalesced across lanes
            a0 = fmaf(xs0[i], f, a0);
            a1 = fmaf(xs1[i], f, a1);
        }
    }
    float mk = (t < C_SZ && nums[t] > 0) ? 1.f : 0.f;
    float e0 = mk * __expf(a0);
    float e1 = mk * __expf(a1);

    float s0 = e0, s1 = e1;
    #pragma unroll
    for (int o = 32; o; o >>= 1) {
        s0 += __shfl_down(s0, o);
        s1 += __shfl_down(s1, o);
    }
    if (lane == 0) { wred[wid] = s0; wred2[wid] = s1; }
    __syncthreads();
    if (t == 0) {
        float z0 = 0.f, z1 = 0.f;
        #pragma unroll
        for (int i = 0; i < 16; ++i) { z0 += wred[i]; z1 += wred2[i]; }
        bc0 = z0; bc1 = z1;
    }
    __syncthreads();
    float inv0 = 1.0f / (bc0 + EPSF);
    float inv1 = 1.0f / (bc1 + EPSF);

    float p1 = 0.f, p2 = 0.f;
    if (t < C_SZ) {
        float lp0 = __logf(e0 * inv0 + EPSF);
        float lp1 = __logf(e1 * inv1 + EPSF);
        p2 = -(soft[(size_t)sr0 * C_SZ + t] * lp0 + soft[(size_t)sr1 * C_SZ + t] * lp1);
        if (t == tgt0) p1 -= lp0;
        if (t == tgt1) p1 -= lp1;
    }
    #pragma unroll
    for (int o = 32; o; o >>= 1) {
        p1 += __shfl_down(p1, o);
        p2 += __shfl_down(p2, o);
    }
    __syncthreads();
    if (lane == 0) { wred[wid] = p1; wred2[wid] = p2; }
    __syncthreads();
    if (t == 0) {
        float z1 = 0.f, z2 = 0.f;
        #pragma unroll
        for (int i = 0; i < 16; ++i) { z1 += wred[i]; z2 += wred2[i]; }
        atomicAdd(&acc[0], z1);
        atomicAdd(&acc[1], z2);
        __threadfence();   // single thread — cheap
        int done = atomicAdd(lcnt, 1);
        if (done == B_SZ / 2 - 1) {
            float l1 = atomicAdd(&acc[0], 0.f) / (float)B_SZ;
            float l2 = atomicAdd(&acc[1], 0.f) / (float)B_SZ;
            out[0] = (cur_epoch[0] == 0) ? l1 : 0.5f * (l1 + l2);
        }
    }
}

extern "C" void kernel_launch(void* const* d_in, const int* in_sizes, int n_in,
                              void* d_out, int out_size, void* d_ws, size_t ws_size,
                              hipStream_t stream) {
    const float* feat     = (const float*)d_in[0];
    const float* features = (const float*)d_in[1];
    const float* soft     = (const float*)d_in[2];
    const int* indexes    = (const int*)d_in[3];
    const int* labels     = (const int*)d_in[4];
    const int* bil        = (const int*)d_in[5];
    const int* cur_epoch  = (const int*)d_in[6];

    char* ws = (char*)d_ws;
    float* fct   = (float*)(ws + OFF_FCT);
    int* nums    = (int*)(ws + OFF_NUMS);
    int* offs    = (int*)(ws + OFF_OFFS);
    int* ctrl    = (int*)(ws + OFF_CTRL);
    int* counts  = (int*)(ws + OFF_COUNTS);
    int* members = (int*)(ws + OFF_MEMB);

    // barriers/ticket/acc must start at 0 every call (d_ws is poisoned 0xAA)
    hipMemsetAsync(ctrl, 0, 24, stream);
    k_all<<<NBLK, 1024, 0, stream>>>(features, labels, feat, soft, indexes, bil,
                                     cur_epoch, fct, nums, offs, counts, members,
                                     ctrl, (float*)d_out);
}

// Round 10
// 49.182 us; speedup vs baseline: 1.6555x; 1.6555x over previous
//
#include <hip/hip_runtime.h>

#define B_SZ 256
#define D_SZ 256
#define M_SZ 65536
#define C_SZ 1000
#define TEMP 0.05f
#define EPSF 1e-6f

#define CPB 4              // classes per csum block
#define NBLK_CSUM (C_SZ / CPB)   // 250
#define LCAP 512           // member-list capacity per class (λ=65.5, ~50σ margin)

// ---- ws layout (bytes) ----
#define OFF_FCT   0          // float[D_SZ*C_SZ] = 1,024,000 B (transposed, pre-scaled)
#define OFF_NUMS  1024000    // int[C_SZ]
#define OFF_ACC   1028000    // float[2]
#define OFF_LCNT  1028008    // int[1] loss ticket

// Self-sufficient classsum: block b owns classes 4b..4b+3.
// Phase 1: scan ALL labels (int4, L2-broadcast across blocks), append matches
//          to per-class LDS lists (cheap compare, no ballot/ffs — R8's cost).
// Phase 2: per-256-thread subgroup, the proven 8-way unrolled row gather,
//          member indices from LDS (broadcast, free).
// Block 0 zeroes acc/lcnt for k_loss (published at kernel boundary).
__launch_bounds__(1024)
__global__ void k_csum(const float* __restrict__ features,
                       const int* __restrict__ labels,
                       float* __restrict__ fct, int* __restrict__ nums,
                       float* __restrict__ acc, int* __restrict__ lcnt) {
    __shared__ int list[CPB][LCAP];
    __shared__ int lcur[CPB];
    int t = threadIdx.x, b = blockIdx.x;
    int c0 = b * CPB;

    if (t < CPB) lcur[t] = 0;
    if (b == 0 && t == 0) { acc[0] = 0.f; acc[1] = 0.f; lcnt[0] = 0; }
    __syncthreads();

    // ---- phase 1: label scan ----
    const int4* L4 = (const int4*)labels;
    #pragma unroll
    for (int k = 0; k < M_SZ / 4 / 1024; ++k) {   // 16 iters
        int idx = k * 1024 + t;
        int4 l4 = L4[idx];
        int m0 = idx * 4;
        unsigned d;
        d = (unsigned)(l4.x - c0); if (d < CPB) list[d][atomicAdd(&lcur[d], 1)] = m0 + 0;
        d = (unsigned)(l4.y - c0); if (d < CPB) list[d][atomicAdd(&lcur[d], 1)] = m0 + 1;
        d = (unsigned)(l4.z - c0); if (d < CPB) list[d][atomicAdd(&lcur[d], 1)] = m0 + 2;
        d = (unsigned)(l4.w - c0); if (d < CPB) list[d][atomicAdd(&lcur[d], 1)] = m0 + 3;
    }
    __syncthreads();

    // ---- phase 2: gather; subgroup g handles class c0+g, dim tt ----
    int g = t >> 8, tt = t & 255;
    int c = c0 + g;
    int n = lcur[g];
    const int* ml = list[g];
    float a0 = 0.f, a1 = 0.f, a2 = 0.f, a3 = 0.f;
    float a4 = 0.f, a5 = 0.f, a6 = 0.f, a7 = 0.f;
    int i = 0;
    for (; i + 8 <= n; i += 8) {
        int r0 = ml[i + 0];
        int r1 = ml[i + 1];
        int r2 = ml[i + 2];
        int r3 = ml[i + 3];
        int r4 = ml[i + 4];
        int r5 = ml[i + 5];
        int r6 = ml[i + 6];
        int r7 = ml[i + 7];
        a0 += features[(size_t)r0 * D_SZ + tt];
        a1 += features[(size_t)r1 * D_SZ + tt];
        a2 += features[(size_t)r2 * D_SZ + tt];
        a3 += features[(size_t)r3 * D_SZ + tt];
        a4 += features[(size_t)r4 * D_SZ + tt];
        a5 += features[(size_t)r5 * D_SZ + tt];
        a6 += features[(size_t)r6 * D_SZ + tt];
        a7 += features[(size_t)r7 * D_SZ + tt];
    }
    for (; i < n; ++i) a0 += features[(size_t)ml[i] * D_SZ + tt];
    float s = ((a0 + a1) + (a2 + a3)) + ((a4 + a5) + (a6 + a7));
    float scale = 1.0f / (TEMP * (float)(n > 0 ? n : 1));
    fct[(size_t)tt * C_SZ + c] = s * scale;
    if (tt == 0) nums[c] = n;
}

// One block (1024 thr) per TWO batch rows (2r, 2r+1); thread t = class t.
// (R7's proven version, unchanged.)
__launch_bounds__(1024)
__global__ void k_loss(const float* __restrict__ feat,
                       const float* __restrict__ fct,
                       const int* __restrict__ nums,
                       const float* __restrict__ soft,
                       const int* __restrict__ indexes,
                       const int* __restrict__ labels,
                       const int* __restrict__ bil,
                       const int* __restrict__ cur_epoch,
                       float* __restrict__ acc, int* __restrict__ lcnt,
                       float* __restrict__ out) {
    __shared__ float xs0[D_SZ], xs1[D_SZ];
    __shared__ float wred[16], wred2[16];
    __shared__ float bc0, bc1;
    __shared__ int tgt0, tgt1, sr0, sr1;

    int t = threadIdx.x;
    int lane = t & 63, wid = t >> 6;
    int r0 = blockIdx.x * 2;

    if (t == 0) {
        tgt0 = labels[indexes[r0]];
        tgt1 = labels[indexes[r0 + 1]];
        sr0 = bil[r0];
        sr1 = bil[r0 + 1];
    }

    // ---- normalize rows 2r,2r+1 (contiguous 512 floats) ----
    float v = (t < 512) ? feat[(size_t)r0 * D_SZ + t] : 0.f;
    float s = v * v;
    #pragma unroll
    for (int o = 32; o; o >>= 1) s += __shfl_down(s, o);
    if (lane == 0) wred[wid] = s;  // waves 0-3 = row0, 4-7 = row1
    __syncthreads();
    if (t == 0) {
        bc0 = fmaxf(sqrtf(wred[0] + wred[1] + wred[2] + wred[3]), 1e-12f);
        bc1 = fmaxf(sqrtf(wred[4] + wred[5] + wred[6] + wred[7]), 1e-12f);
    }
    __syncthreads();
    if (t < 256) xs0[t] = v / bc0;
    else if (t < 512) xs1[t - 256] = v / bc1;
    __syncthreads();

    // ---- sim + exp for class t, both rows ----
    float a0 = 0.f, a1 = 0.f;
    if (t < C_SZ) {
        #pragma unroll 8
        for (int i = 0; i < D_SZ; ++i) {
            float f = fct[(size_t)i * C_SZ + t];  // coalesced across lanes
            a0 = fmaf(xs0[i], f, a0);
            a1 = fmaf(xs1[i], f, a1);
        }
    }
    float mk = (t < C_SZ && nums[t] > 0) ? 1.f : 0.f;
    float e0 = mk * __expf(a0);
    float e1 = mk * __expf(a1);

    // ---- denominators over classes (both rows at once) ----
    float s0 = e0, s1 = e1;
    #pragma unroll
    for (int o = 32; o; o >>= 1) {
        s0 += __shfl_down(s0, o);
        s1 += __shfl_down(s1, o);
    }
    if (lane == 0) { wred[wid] = s0; wred2[wid] = s1; }
    __syncthreads();
    if (t == 0) {
        float z0 = 0.f, z1 = 0.f;
        #pragma unroll
        for (int i = 0; i < 16; ++i) { z0 += wred[i]; z1 += wred2[i]; }
        bc0 = z0; bc1 = z1;
    }
    __syncthreads();
    float inv0 = 1.0f / (bc0 + EPSF);
    float inv1 = 1.0f / (bc1 + EPSF);

    // ---- loss partials ----
    float p1 = 0.f, p2 = 0.f;
    if (t < C_SZ) {
        float lp0 = __logf(e0 * inv0 + EPSF);
        float lp1 = __logf(e1 * inv1 + EPSF);
        p2 = -(soft[(size_t)sr0 * C_SZ + t] * lp0 + soft[(size_t)sr1 * C_SZ + t] * lp1);
        if (t == tgt0) p1 -= lp0;
        if (t == tgt1) p1 -= lp1;
    }
    #pragma unroll
    for (int o = 32; o; o >>= 1) {
        p1 += __shfl_down(p1, o);
        p2 += __shfl_down(p2, o);
    }
    __syncthreads();
    if (lane == 0) { wred[wid] = p1; wred2[wid] = p2; }
    __syncthreads();
    if (t == 0) {
        float z1 = 0.f, z2 = 0.f;
        #pragma unroll
        for (int i = 0; i < 16; ++i) { z1 += wred[i]; z2 += wred2[i]; }
        atomicAdd(&acc[0], z1);
        atomicAdd(&acc[1], z2);
        __threadfence();
        int done = atomicAdd(lcnt, 1);
        if (done == (int)gridDim.x - 1) {
            float l1 = atomicAdd(&acc[0], 0.f) / (float)B_SZ;
            float l2 = atomicAdd(&acc[1], 0.f) / (float)B_SZ;
            out[0] = (cur_epoch[0] == 0) ? l1 : 0.5f * (l1 + l2);
        }
    }
}

extern "C" void kernel_launch(void* const* d_in, const int* in_sizes, int n_in,
                              void* d_out, int out_size, void* d_ws, size_t ws_size,
                              hipStream_t stream) {
    const float* feat     = (const float*)d_in[0];
    const float* features = (const float*)d_in[1];
    const float* soft     = (const float*)d_in[2];
    const int* indexes    = (const int*)d_in[3];
    const int* labels     = (const int*)d_in[4];
    const int* bil        = (const int*)d_in[5];
    const int* cur_epoch  = (const int*)d_in[6];

    char* ws = (char*)d_ws;
    float* fct   = (float*)(ws + OFF_FCT);
    int* nums    = (int*)(ws + OFF_NUMS);
    float* acc   = (float*)(ws + OFF_ACC);
    int* lcnt    = (int*)(ws + OFF_LCNT);

    k_csum<<<NBLK_CSUM, 1024, 0, stream>>>(features, labels, fct, nums, acc, lcnt);
    k_loss<<<B_SZ / 2, 1024, 0, stream>>>(feat, fct, nums, soft, indexes, labels,
                                          bil, cur_epoch, acc, lcnt, (float*)d_out);
}

// Round 11
// 41.411 us; speedup vs baseline: 1.9661x; 1.1877x over previous
//
#include <hip/hip_runtime.h>

#define B_SZ 256
#define D_SZ 256
#define M_SZ 65536
#define C_SZ 1000
#define TEMP 0.05f
#define EPSF 1e-6f

#define CPB 2                    // classes per csum block
#define NBLK_CSUM (C_SZ / CPB)   // 500 blocks -> ~2 blocks/CU during gather
#define LCAP 512                 // member-list capacity (lambda=65.5, huge margin)

// packed fct layout: float index (d>>2)*(C_SZ*4) + c*4 + (d&3)
// -> float4 unit index (d>>2)*C_SZ + c

// ---- ws layout (bytes) ----
#define OFF_FCT   0          // float[D_SZ*C_SZ] = 1,024,000 B (packed layout)
#define OFF_NUMS  1024000    // int[C_SZ]
#define OFF_ACC   1028000    // float[2]
#define OFF_LCNT  1028008    // int[1] loss ticket

// Self-sufficient classsum: block b owns classes 2b, 2b+1.
// Phase 1: all 1024 threads scan all labels (int4, L2-broadcast), append
//          matches to per-class LDS lists.
// Phase 2: per class, 512 threads = 8 row-streams x 64 lanes; each lane
//          gathers a float4 (16B) slice of its stream's rows -> 8 rows in
//          flight, 4x fewer VMEM ops than scalar. 8-way LDS tree reduce,
//          write packed float4 to fct.
__launch_bounds__(1024)
__global__ void k_csum(const float* __restrict__ features,
                       const int* __restrict__ labels,
                       float* __restrict__ fct, int* __restrict__ nums,
                       float* __restrict__ acc, int* __restrict__ lcnt) {
    __shared__ int list[CPB][LCAP];
    __shared__ int lcur[CPB];
    __shared__ float4 red[CPB][8][64];   // 16 KB
    int t = threadIdx.x, b = blockIdx.x;
    int c0 = b * CPB;

    if (t < CPB) lcur[t] = 0;
    if (b == 0 && t == 0) { acc[0] = 0.f; acc[1] = 0.f; lcnt[0] = 0; }
    __syncthreads();

    // ---- phase 1: label scan ----
    const int4* L4 = (const int4*)labels;
    #pragma unroll
    for (int k = 0; k < M_SZ / 4 / 1024; ++k) {   // 16 iters
        int idx = k * 1024 + t;
        int4 l4 = L4[idx];
        int m0 = idx * 4;
        unsigned d;
        d = (unsigned)(l4.x - c0); if (d < CPB) list[d][atomicAdd(&lcur[d], 1)] = m0 + 0;
        d = (unsigned)(l4.y - c0); if (d < CPB) list[d][atomicAdd(&lcur[d], 1)] = m0 + 1;
        d = (unsigned)(l4.z - c0); if (d < CPB) list[d][atomicAdd(&lcur[d], 1)] = m0 + 2;
        d = (unsigned)(l4.w - c0); if (d < CPB) list[d][atomicAdd(&lcur[d], 1)] = m0 + 3;
    }
    __syncthreads();

    // ---- phase 2: float4 gather ----
    int g = t >> 9;          // class subgroup (0/1)
    int tt = t & 511;
    int s = tt >> 6;         // row stream 0..7
    int lane = tt & 63;      // 16B slice of the row
    int c = c0 + g;
    int n = lcur[g];
    const int* ml = list[g];
    float4 a = make_float4(0.f, 0.f, 0.f, 0.f);
    #pragma unroll 2
    for (int i = s; i < n; i += 8) {
        float4 v = *(const float4*)&features[(size_t)ml[i] * D_SZ + lane * 4];
        a.x += v.x; a.y += v.y; a.z += v.z; a.w += v.w;
    }
    red[g][s][lane] = a;
    __syncthreads();
    if (s == 0) {
        float4 z = make_float4(0.f, 0.f, 0.f, 0.f);
        #pragma unroll
        for (int q = 0; q < 8; ++q) {
            float4 r = red[g][q][lane];
            z.x += r.x; z.y += r.y; z.z += r.z; z.w += r.w;
        }
        float scale = 1.0f / (TEMP * (float)(n > 0 ? n : 1));
        z.x *= scale; z.y *= scale; z.z *= scale; z.w *= scale;
        // packed: dims 4*lane..4*lane+3 for class c
        *(float4*)&fct[(size_t)lane * (C_SZ * 4) + c * 4] = z;
        if (lane == 0) nums[c] = n;
    }
}

// One block (1024 thr) per TWO batch rows; thread t = class t. fct read as
// 64 float4 loads (packed layout, wave reads contiguous 1KB) instead of 256
// scalars. Otherwise R7's proven body.
__launch_bounds__(1024)
__global__ void k_loss(const float* __restrict__ feat,
                       const float* __restrict__ fct,
                       const int* __restrict__ nums,
                       const float* __restrict__ soft,
                       const int* __restrict__ indexes,
                       const int* __restrict__ labels,
                       const int* __restrict__ bil,
                       const int* __restrict__ cur_epoch,
                       float* __restrict__ acc, int* __restrict__ lcnt,
                       float* __restrict__ out) {
    __shared__ float xs0[D_SZ], xs1[D_SZ];
    __shared__ float wred[16], wred2[16];
    __shared__ float bc0, bc1;
    __shared__ int tgt0, tgt1, sr0, sr1;

    int t = threadIdx.x;
    int lane = t & 63, wid = t >> 6;
    int r0 = blockIdx.x * 2;

    if (t == 0) {
        tgt0 = labels[indexes[r0]];
        tgt1 = labels[indexes[r0 + 1]];
        sr0 = bil[r0];
        sr1 = bil[r0 + 1];
    }

    // ---- normalize rows 2r,2r+1 (contiguous 512 floats) ----
    float v = (t < 512) ? feat[(size_t)r0 * D_SZ + t] : 0.f;
    float s = v * v;
    #pragma unroll
    for (int o = 32; o; o >>= 1) s += __shfl_down(s, o);
    if (lane == 0) wred[wid] = s;  // waves 0-3 = row0, 4-7 = row1
    __syncthreads();
    if (t == 0) {
        bc0 = fmaxf(sqrtf(wred[0] + wred[1] + wred[2] + wred[3]), 1e-12f);
        bc1 = fmaxf(sqrtf(wred[4] + wred[5] + wred[6] + wred[7]), 1e-12f);
    }
    __syncthreads();
    if (t < 256) xs0[t] = v / bc0;
    else if (t < 512) xs1[t - 256] = v / bc1;
    __syncthreads();

    // ---- sim + exp for class t, both rows (float4 over d) ----
    float a0 = 0.f, a1 = 0.f;
    if (t < C_SZ) {
        const float4* F = (const float4*)fct;   // unit index (d>>2)*C_SZ + c
        #pragma unroll 4
        for (int j = 0; j < D_SZ / 4; ++j) {
            float4 f4 = F[(size_t)j * C_SZ + t];        // coalesced 1KB/wave
            float4 x0 = *(const float4*)&xs0[4 * j];    // ds_read_b128
            float4 x1 = *(const float4*)&xs1[4 * j];
            a0 = fmaf(x0.x, f4.x, a0); a0 = fmaf(x0.y, f4.y, a0);
            a0 = fmaf(x0.z, f4.z, a0); a0 = fmaf(x0.w, f4.w, a0);
            a1 = fmaf(x1.x, f4.x, a1); a1 = fmaf(x1.y, f4.y, a1);
            a1 = fmaf(x1.z, f4.z, a1); a1 = fmaf(x1.w, f4.w, a1);
        }
    }
    float mk = (t < C_SZ && nums[t] > 0) ? 1.f : 0.f;
    float e0 = mk * __expf(a0);
    float e1 = mk * __expf(a1);

    // ---- denominators over classes (both rows at once) ----
    float s0 = e0, s1 = e1;
    #pragma unroll
    for (int o = 32; o; o >>= 1) {
        s0 += __shfl_down(s0, o);
        s1 += __shfl_down(s1, o);
    }
    if (lane == 0) { wred[wid] = s0; wred2[wid] = s1; }
    __syncthreads();
    if (t == 0) {
        float z0 = 0.f, z1 = 0.f;
        #pragma unroll
        for (int i = 0; i < 16; ++i) { z0 += wred[i]; z1 += wred2[i]; }
        bc0 = z0; bc1 = z1;
    }
    __syncthreads();
    float inv0 = 1.0f / (bc0 + EPSF);
    float inv1 = 1.0f / (bc1 + EPSF);

    // ---- loss partials ----
    float p1 = 0.f, p2 = 0.f;
    if (t < C_SZ) {
        float lp0 = __logf(e0 * inv0 + EPSF);
        float lp1 = __logf(e1 * inv1 + EPSF);
        p2 = -(soft[(size_t)sr0 * C_SZ + t] * lp0 + soft[(size_t)sr1 * C_SZ + t] * lp1);
        if (t == tgt0) p1 -= lp0;
        if (t == tgt1) p1 -= lp1;
    }
    #pragma unroll
    for (int o = 32; o; o >>= 1) {
        p1 += __shfl_down(p1, o);
        p2 += __shfl_down(p2, o);
    }
    __syncthreads();
    if (lane == 0) { wred[wid] = p1; wred2[wid] = p2; }
    __syncthreads();
    if (t == 0) {
        float z1 = 0.f, z2 = 0.f;
        #pragma unroll
        for (int i = 0; i < 16; ++i) { z1 += wred[i]; z2 += wred2[i]; }
        atomicAdd(&acc[0], z1);
        atomicAdd(&acc[1], z2);
        __threadfence();
        int done = atomicAdd(lcnt, 1);
        if (done == (int)gridDim.x - 1) {
            float l1 = atomicAdd(&acc[0], 0.f) / (float)B_SZ;
            float l2 = atomicAdd(&acc[1], 0.f) / (float)B_SZ;
            out[0] = (cur_epoch[0] == 0) ? l1 : 0.5f * (l1 + l2);
        }
    }
}

extern "C" void kernel_launch(void* const* d_in, const int* in_sizes, int n_in,
                              void* d_out, int out_size, void* d_ws, size_t ws_size,
                              hipStream_t stream) {
    const float* feat     = (const float*)d_in[0];
    const float* features = (const float*)d_in[1];
    const float* soft     = (const float*)d_in[2];
    const int* indexes    = (const int*)d_in[3];
    const int* labels     = (const int*)d_in[4];
    const int* bil        = (const int*)d_in[5];
    const int* cur_epoch  = (const int*)d_in[6];

    char* ws = (char*)d_ws;
    float* fct   = (float*)(ws + OFF_FCT);
    int* nums    = (int*)(ws + OFF_NUMS);
    float* acc   = (float*)(ws + OFF_ACC);
    int* lcnt    = (int*)(ws + OFF_LCNT);

    k_csum<<<NBLK_CSUM, 1024, 0, stream>>>(features, labels, fct, nums, acc, lcnt);
    k_loss<<<B_SZ / 2, 1024, 0, stream>>>(feat, fct, nums, soft, indexes, labels,
                                          bil, cur_epoch, acc, lcnt, (float*)d_out);
}

// Round 12
// 40.511 us; speedup vs baseline: 2.0098x; 1.0222x over previous
//
#include <hip/hip_runtime.h>
#include <hip/hip_bf16.h>

#define B_SZ 256
#define D_SZ 256
#define M_SZ 65536
#define C_SZ 1000
#define TEMP 0.05f
#define EPSF 1e-6f

#define CPB 2                    // classes per csum block
#define NBLK_CSUM (C_SZ / CPB)   // 500 blocks -> ~2 blocks/CU during gather
#define LCAP 512                 // member-list capacity (lambda=65.5, huge margin)

// packed bf16 fct layout: ushort index (d>>2)*(C_SZ*4) + c*4 + (d&3)
// -> ushort4 unit index (d>>2)*C_SZ + c  (8 B per class-dim-quad)

// ---- ws layout (bytes) ----
#define OFF_FCT   0          // ushort[D_SZ*C_SZ] = 512,000 B (packed bf16)
#define OFF_NUMS  512000     // int[C_SZ]
#define OFF_ACC   516000     // float[2]
#define OFF_LCNT  516008     // int[1] loss ticket

static __device__ __forceinline__ unsigned short f2bf(float f) {
    __hip_bfloat16 h = __float2bfloat16(f);   // RNE
    return *reinterpret_cast<unsigned short*>(&h);
}
static __device__ __forceinline__ float bf2f(unsigned short u) {
    return __uint_as_float((unsigned)u << 16);  // exact
}

// Self-sufficient classsum: block b owns classes 2b, 2b+1.
// Phase 1: all 1024 threads scan all labels (int4, L2-broadcast), append
//          matches to per-class LDS lists.
// Phase 2: per class, 512 threads = 8 row-streams x 64 lanes; lane gathers a
//          float4 slice per row. 8-way LDS tree reduce; write packed bf16.
__launch_bounds__(1024)
__global__ void k_csum(const float* __restrict__ features,
                       const int* __restrict__ labels,
                       unsigned short* __restrict__ fct, int* __restrict__ nums,
                       float* __restrict__ acc, int* __restrict__ lcnt) {
    __shared__ int list[CPB][LCAP];
    __shared__ int lcur[CPB];
    __shared__ float4 red[CPB][8][64];   // 16 KB
    int t = threadIdx.x, b = blockIdx.x;
    int c0 = b * CPB;

    if (t < CPB) lcur[t] = 0;
    if (b == 0 && t == 0) { acc[0] = 0.f; acc[1] = 0.f; lcnt[0] = 0; }
    __syncthreads();

    // ---- phase 1: label scan ----
    const int4* L4 = (const int4*)labels;
    #pragma unroll
    for (int k = 0; k < M_SZ / 4 / 1024; ++k) {   // 16 iters
        int idx = k * 1024 + t;
        int4 l4 = L4[idx];
        int m0 = idx * 4;
        unsigned d;
        d = (unsigned)(l4.x - c0); if (d < CPB) list[d][atomicAdd(&lcur[d], 1)] = m0 + 0;
        d = (unsigned)(l4.y - c0); if (d < CPB) list[d][atomicAdd(&lcur[d], 1)] = m0 + 1;
        d = (unsigned)(l4.z - c0); if (d < CPB) list[d][atomicAdd(&lcur[d], 1)] = m0 + 2;
        d = (unsigned)(l4.w - c0); if (d < CPB) list[d][atomicAdd(&lcur[d], 1)] = m0 + 3;
    }
    __syncthreads();

    // ---- phase 2: float4 gather ----
    int g = t >> 9;          // class subgroup (0/1)
    int tt = t & 511;
    int s = tt >> 6;         // row stream 0..7
    int lane = tt & 63;      // 16B slice of the row
    int c = c0 + g;
    int n = lcur[g];
    const int* ml = list[g];
    float4 a = make_float4(0.f, 0.f, 0.f, 0.f);
    #pragma unroll 2
    for (int i = s; i < n; i += 8) {
        float4 v = *(const float4*)&features[(size_t)ml[i] * D_SZ + lane * 4];
        a.x += v.x; a.y += v.y; a.z += v.z; a.w += v.w;
    }
    red[g][s][lane] = a;
    __syncthreads();
    if (s == 0) {
        float4 z = make_float4(0.f, 0.f, 0.f, 0.f);
        #pragma unroll
        for (int q = 0; q < 8; ++q) {
            float4 r = red[g][q][lane];
            z.x += r.x; z.y += r.y; z.z += r.z; z.w += r.w;
        }
        float scale = 1.0f / (TEMP * (float)(n > 0 ? n : 1));
        ushort4 o;
        o.x = f2bf(z.x * scale); o.y = f2bf(z.y * scale);
        o.z = f2bf(z.z * scale); o.w = f2bf(z.w * scale);
        // packed: dims 4*lane..4*lane+3 for class c  (8B aligned store)
        *(ushort4*)&fct[(size_t)lane * (C_SZ * 4) + c * 4] = o;
        if (lane == 0) nums[c] = n;
    }
}

// One block (1024 thr) per TWO batch rows; thread t = class t. fct read as
// 64 ushort4 (8B) loads — half the L3 traffic of fp32. Otherwise R7's body.
__launch_bounds__(1024)
__global__ void k_loss(const float* __restrict__ feat,
                       const unsigned short* __restrict__ fct,
                       const int* __restrict__ nums,
                       const float* __restrict__ soft,
                       const int* __restrict__ indexes,
                       const int* __restrict__ labels,
                       const int* __restrict__ bil,
                       const int* __restrict__ cur_epoch,
                       float* __restrict__ acc, int* __restrict__ lcnt,
                       float* __restrict__ out) {
    __shared__ float xs0[D_SZ], xs1[D_SZ];
    __shared__ float wred[16], wred2[16];
    __shared__ float bc0, bc1;
    __shared__ int tgt0, tgt1, sr0, sr1;

    int t = threadIdx.x;
    int lane = t & 63, wid = t >> 6;
    int r0 = blockIdx.x * 2;

    if (t == 0) {
        tgt0 = labels[indexes[r0]];
        tgt1 = labels[indexes[r0 + 1]];
        sr0 = bil[r0];
        sr1 = bil[r0 + 1];
    }

    // ---- normalize rows 2r,2r+1 (contiguous 512 floats) ----
    float v = (t < 512) ? feat[(size_t)r0 * D_SZ + t] : 0.f;
    float s = v * v;
    #pragma unroll
    for (int o = 32; o; o >>= 1) s += __shfl_down(s, o);
    if (lane == 0) wred[wid] = s;  // waves 0-3 = row0, 4-7 = row1
    __syncthreads();
    if (t == 0) {
        bc0 = fmaxf(sqrtf(wred[0] + wred[1] + wred[2] + wred[3]), 1e-12f);
        bc1 = fmaxf(sqrtf(wred[4] + wred[5] + wred[6] + wred[7]), 1e-12f);
    }
    __syncthreads();
    if (t < 256) xs0[t] = v / bc0;
    else if (t < 512) xs1[t - 256] = v / bc1;
    __syncthreads();

    // ---- sim + exp for class t, both rows (bf16x4 over d) ----
    float a0 = 0.f, a1 = 0.f;
    if (t < C_SZ) {
        const ushort4* F = (const ushort4*)fct;   // unit index (d>>2)*C_SZ + c
        #pragma unroll 4
        for (int j = 0; j < D_SZ / 4; ++j) {
            ushort4 u = F[(size_t)j * C_SZ + t];        // coalesced 512B/wave
            float4 x0 = *(const float4*)&xs0[4 * j];    // ds_read_b128
            float4 x1 = *(const float4*)&xs1[4 * j];
            float fx = bf2f(u.x), fy = bf2f(u.y), fz = bf2f(u.z), fw = bf2f(u.w);
            a0 = fmaf(x0.x, fx, a0); a0 = fmaf(x0.y, fy, a0);
            a0 = fmaf(x0.z, fz, a0); a0 = fmaf(x0.w, fw, a0);
            a1 = fmaf(x1.x, fx, a1); a1 = fmaf(x1.y, fy, a1);
            a1 = fmaf(x1.z, fz, a1); a1 = fmaf(x1.w, fw, a1);
        }
    }
    float mk = (t < C_SZ && nums[t] > 0) ? 1.f : 0.f;
    float e0 = mk * __expf(a0);
    float e1 = mk * __expf(a1);

    // ---- denominators over classes (both rows at once) ----
    float s0 = e0, s1 = e1;
    #pragma unroll
    for (int o = 32; o; o >>= 1) {
        s0 += __shfl_down(s0, o);
        s1 += __shfl_down(s1, o);
    }
    if (lane == 0) { wred[wid] = s0; wred2[wid] = s1; }
    __syncthreads();
    if (t == 0) {
        float z0 = 0.f, z1 = 0.f;
        #pragma unroll
        for (int i = 0; i < 16; ++i) { z0 += wred[i]; z1 += wred2[i]; }
        bc0 = z0; bc1 = z1;
    }
    __syncthreads();
    float inv0 = 1.0f / (bc0 + EPSF);
    float inv1 = 1.0f / (bc1 + EPSF);

    // ---- loss partials ----
    float p1 = 0.f, p2 = 0.f;
    if (t < C_SZ) {
        float lp0 = __logf(e0 * inv0 + EPSF);
        float lp1 = __logf(e1 * inv1 + EPSF);
        p2 = -(soft[(size_t)sr0 * C_SZ + t] * lp0 + soft[(size_t)sr1 * C_SZ + t] * lp1);
        if (t == tgt0) p1 -= lp0;
        if (t == tgt1) p1 -= lp1;
    }
    #pragma unroll
    for (int o = 32; o; o >>= 1) {
        p1 += __shfl_down(p1, o);
        p2 += __shfl_down(p2, o);
    }
    __syncthreads();
    if (lane == 0) { wred[wid] = p1; wred2[wid] = p2; }
    __syncthreads();
    if (t == 0) {
        float z1 = 0.f, z2 = 0.f;
        #pragma unroll
        for (int i = 0; i < 16; ++i) { z1 += wred[i]; z2 += wred2[i]; }
        atomicAdd(&acc[0], z1);
        atomicAdd(&acc[1], z2);
        __threadfence();
        int done = atomicAdd(lcnt, 1);
        if (done == (int)gridDim.x - 1) {
            float l1 = atomicAdd(&acc[0], 0.f) / (float)B_SZ;
            float l2 = atomicAdd(&acc[1], 0.f) / (float)B_SZ;
            out[0] = (cur_epoch[0] == 0) ? l1 : 0.5f * (l1 + l2);
        }
    }
}

extern "C" void kernel_launch(void* const* d_in, const int* in_sizes, int n_in,
                              void* d_out, int out_size, void* d_ws, size_t ws_size,
                              hipStream_t stream) {
    const float* feat     = (const float*)d_in[0];
    const float* features = (const float*)d_in[1];
    const float* soft     = (const float*)d_in[2];
    const int* indexes    = (const int*)d_in[3];
    const int* labels     = (const int*)d_in[4];
    const int* bil        = (const int*)d_in[5];
    const int* cur_epoch  = (const int*)d_in[6];

    char* ws = (char*)d_ws;
    unsigned short* fct = (unsigned short*)(ws + OFF_FCT);
    int* nums    = (int*)(ws + OFF_NUMS);
    float* acc   = (float*)(ws + OFF_ACC);
    int* lcnt    = (int*)(ws + OFF_LCNT);

    k_csum<<<NBLK_CSUM, 1024, 0, stream>>>(features, labels, fct, nums, acc, lcnt);
    k_loss<<<B_SZ / 2, 1024, 0, stream>>>(feat, fct, nums, soft, indexes, labels,
                                          bil, cur_epoch, acc, lcnt, (float*)d_out);
}

// Round 13
// 39.681 us; speedup vs baseline: 2.0519x; 1.0209x over previous
//
#include <hip/hip_runtime.h>
#include <hip/hip_bf16.h>

#define B_SZ 256
#define D_SZ 256
#define M_SZ 65536
#define C_SZ 1000
#define TEMP 0.05f
#define EPSF 1e-6f

#define CPB 2                    // classes per csum block
#define NBLK_CSUM (C_SZ / CPB)   // 500 blocks -> ~2 blocks/CU during gather
#define LCAP 512                 // member-list capacity (lambda=65.5, huge margin)

// packed bf16 fct layout: ushort index (d>>2)*(C_SZ*4) + c*4 + (d&3)
// -> for dim-quad j, classes c0..c0+3 are 32 contiguous bytes (two int4)

// ---- ws layout (bytes) ----
#define OFF_FCT   0          // ushort[D_SZ*C_SZ] = 512,000 B (packed bf16)
#define OFF_NUMS  512000     // int[C_SZ]
#define OFF_ACC   516000     // float[2]
#define OFF_LCNT  516008     // int[1] loss ticket

static __device__ __forceinline__ unsigned short f2bf(float f) {
    __hip_bfloat16 h = __float2bfloat16(f);   // RNE
    return *reinterpret_cast<unsigned short*>(&h);
}
#define BFLO(u) __uint_as_float(((unsigned)(u)) << 16)        // low ushort -> f32 (exact)
#define BFHI(u) __uint_as_float(((unsigned)(u)) & 0xffff0000u) // high ushort -> f32 (exact)

// Self-sufficient classsum (R11 structure; gather unroll 2->4 for 4 chains
// of ml[i](LDS) -> features(HBM) in flight).
__launch_bounds__(1024)
__global__ void k_csum(const float* __restrict__ features,
                       const int* __restrict__ labels,
                       unsigned short* __restrict__ fct, int* __restrict__ nums,
                       float* __restrict__ acc, int* __restrict__ lcnt) {
    __shared__ int list[CPB][LCAP];
    __shared__ int lcur[CPB];
    __shared__ float4 red[CPB][8][64];   // 16 KB
    int t = threadIdx.x, b = blockIdx.x;
    int c0 = b * CPB;

    if (t < CPB) lcur[t] = 0;
    if (b == 0 && t == 0) { acc[0] = 0.f; acc[1] = 0.f; lcnt[0] = 0; }
    __syncthreads();

    // ---- phase 1: label scan ----
    const int4* L4 = (const int4*)labels;
    #pragma unroll
    for (int k = 0; k < M_SZ / 4 / 1024; ++k) {   // 16 iters
        int idx = k * 1024 + t;
        int4 l4 = L4[idx];
        int m0 = idx * 4;
        unsigned d;
        d = (unsigned)(l4.x - c0); if (d < CPB) list[d][atomicAdd(&lcur[d], 1)] = m0 + 0;
        d = (unsigned)(l4.y - c0); if (d < CPB) list[d][atomicAdd(&lcur[d], 1)] = m0 + 1;
        d = (unsigned)(l4.z - c0); if (d < CPB) list[d][atomicAdd(&lcur[d], 1)] = m0 + 2;
        d = (unsigned)(l4.w - c0); if (d < CPB) list[d][atomicAdd(&lcur[d], 1)] = m0 + 3;
    }
    __syncthreads();

    // ---- phase 2: float4 gather, 4 iterations in flight ----
    int g = t >> 9;          // class subgroup (0/1)
    int tt = t & 511;
    int s = tt >> 6;         // row stream 0..7
    int lane = tt & 63;      // 16B slice of the row
    int c = c0 + g;
    int n = lcur[g];
    const int* ml = list[g];
    float4 a = make_float4(0.f, 0.f, 0.f, 0.f);
    #pragma unroll 4
    for (int i = s; i < n; i += 8) {
        float4 v = *(const float4*)&features[(size_t)ml[i] * D_SZ + lane * 4];
        a.x += v.x; a.y += v.y; a.z += v.z; a.w += v.w;
    }
    red[g][s][lane] = a;
    __syncthreads();
    if (s == 0) {
        float4 z = make_float4(0.f, 0.f, 0.f, 0.f);
        #pragma unroll
        for (int q = 0; q < 8; ++q) {
            float4 r = red[g][q][lane];
            z.x += r.x; z.y += r.y; z.z += r.z; z.w += r.w;
        }
        float scale = 1.0f / (TEMP * (float)(n > 0 ? n : 1));
        ushort4 o;
        o.x = f2bf(z.x * scale); o.y = f2bf(z.y * scale);
        o.z = f2bf(z.z * scale); o.w = f2bf(z.w * scale);
        *(ushort4*)&fct[(size_t)lane * (C_SZ * 4) + c * 4] = o;
        if (lane == 0) nums[c] = n;
    }
}

// 128 blocks x 1024 thr, 2 rows/block. Thread t: dim-chunk q = t>>8 (64 dims),
// class-quad c0 = 4*(t&255). DS traffic per block: 2MB -> 512KB (the R12
// bottleneck). Partials via padded pa[4][256][9].
__launch_bounds__(1024)
__global__ void k_loss(const float* __restrict__ feat,
                       const unsigned short* __restrict__ fct,
                       const int* __restrict__ nums,
                       const float* __restrict__ soft,
                       const int* __restrict__ indexes,
                       const int* __restrict__ labels,
                       const int* __restrict__ bil,
                       const int* __restrict__ cur_epoch,
                       float* __restrict__ acc, int* __restrict__ lcnt,
                       float* __restrict__ out) {
    __shared__ float xs0[D_SZ], xs1[D_SZ];
    __shared__ float pa[4][256][9];   // [q][tt][cls*2+row], pad 9 -> no bank conflict
    __shared__ float wred[16], wred2[16];
    __shared__ float bc0, bc1;
    __shared__ int tgt0, tgt1, sr0, sr1;

    int t = threadIdx.x;
    int lane = t & 63, wid = t >> 6;
    int r0 = blockIdx.x * 2;

    if (t == 0) {
        tgt0 = labels[indexes[r0]];
        tgt1 = labels[indexes[r0 + 1]];
        sr0 = bil[r0];
        sr1 = bil[r0 + 1];
    }

    // ---- normalize rows 2r,2r+1 (contiguous 512 floats) ----
    float v = (t < 512) ? feat[(size_t)r0 * D_SZ + t] : 0.f;
    float s = v * v;
    #pragma unroll
    for (int o = 32; o; o >>= 1) s += __shfl_down(s, o);
    if (lane == 0) wred[wid] = s;  // waves 0-3 = row0, 4-7 = row1
    __syncthreads();
    if (t == 0) {
        bc0 = fmaxf(sqrtf(wred[0] + wred[1] + wred[2] + wred[3]), 1e-12f);
        bc1 = fmaxf(sqrtf(wred[4] + wred[5] + wred[6] + wred[7]), 1e-12f);
    }
    __syncthreads();
    if (t < 256) xs0[t] = v / bc0;
    else if (t < 512) xs1[t - 256] = v / bc1;
    __syncthreads();

    // ---- phase B: partial sims for 4 classes x 2 rows over my 64 dims ----
    int q = t >> 8, tt = t & 255;
    int c0 = 4 * tt;
    float b00 = 0.f, b01 = 0.f, b02 = 0.f, b03 = 0.f;   // row0, cls 0..3
    float b10 = 0.f, b11 = 0.f, b12 = 0.f, b13 = 0.f;   // row1
    if (tt < 250) {
        int jb = q * 16;
        #pragma unroll 4
        for (int j = jb; j < jb + 16; ++j) {
            const unsigned short* base = fct + (size_t)j * (C_SZ * 4) + c0 * 4;
            int4 u0 = *(const int4*)base;        // cls c0, c0+1 (dims 4j..4j+3)
            int4 u1 = *(const int4*)(base + 8);  // cls c0+2, c0+3
            float4 x0 = *(const float4*)&xs0[4 * j];
            float4 x1 = *(const float4*)&xs1[4 * j];
            float f0, f1, f2, f3;
            f0 = BFLO(u0.x); f1 = BFHI(u0.x); f2 = BFLO(u0.y); f3 = BFHI(u0.y);
            b00 = fmaf(x0.x, f0, b00); b00 = fmaf(x0.y, f1, b00);
            b00 = fmaf(x0.z, f2, b00); b00 = fmaf(x0.w, f3, b00);
            b10 = fmaf(x1.x, f0, b10); b10 = fmaf(x1.y, f1, b10);
            b10 = fmaf(x1.z, f2, b10); b10 = fmaf(x1.w, f3, b10);
            f0 = BFLO(u0.z); f1 = BFHI(u0.z); f2 = BFLO(u0.w); f3 = BFHI(u0.w);
            b01 = fmaf(x0.x, f0, b01); b01 = fmaf(x0.y, f1, b01);
            b01 = fmaf(x0.z, f2, b01); b01 = fmaf(x0.w, f3, b01);
            b11 = fmaf(x1.x, f0, b11); b11 = fmaf(x1.y, f1, b11);
            b11 = fmaf(x1.z, f2, b11); b11 = fmaf(x1.w, f3, b11);
            f0 = BFLO(u1.x); f1 = BFHI(u1.x); f2 = BFLO(u1.y); f3 = BFHI(u1.y);
            b02 = fmaf(x0.x, f0, b02); b02 = fmaf(x0.y, f1, b02);
            b02 = fmaf(x0.z, f2, b02); b02 = fmaf(x0.w, f3, b02);
            b12 = fmaf(x1.x, f0, b12); b12 = fmaf(x1.y, f1, b12);
            b12 = fmaf(x1.z, f2, b12); b12 = fmaf(x1.w, f3, b12);
            f0 = BFLO(u1.z); f1 = BFHI(u1.z); f2 = BFLO(u1.w); f3 = BFHI(u1.w);
            b03 = fmaf(x0.x, f0, b03); b03 = fmaf(x0.y, f1, b03);
            b03 = fmaf(x0.z, f2, b03); b03 = fmaf(x0.w, f3, b03);
            b13 = fmaf(x1.x, f0, b13); b13 = fmaf(x1.y, f1, b13);
            b13 = fmaf(x1.z, f2, b13); b13 = fmaf(x1.w, f3, b13);
        }
    }
    pa[q][tt][0] = b00; pa[q][tt][1] = b10;
    pa[q][tt][2] = b01; pa[q][tt][3] = b11;
    pa[q][tt][4] = b02; pa[q][tt][5] = b12;
    pa[q][tt][6] = b03; pa[q][tt][7] = b13;
    __syncthreads();

    // ---- phase C: reduce partials, masked exp (threads t<250 active) ----
    float e0[4] = {0.f, 0.f, 0.f, 0.f};
    float e1[4] = {0.f, 0.f, 0.f, 0.f};
    float s0 = 0.f, s1 = 0.f;
    if (t < 250) {
        int4 nm = *(const int4*)&nums[4 * t];
        #pragma unroll
        for (int k = 0; k < 4; ++k) {
            float a0 = (pa[0][t][2 * k] + pa[1][t][2 * k]) +
                       (pa[2][t][2 * k] + pa[3][t][2 * k]);
            float a1 = (pa[0][t][2 * k + 1] + pa[1][t][2 * k + 1]) +
                       (pa[2][t][2 * k + 1] + pa[3][t][2 * k + 1]);
            int nk = (k == 0) ? nm.x : (k == 1) ? nm.y : (k == 2) ? nm.z : nm.w;
            float mk = (nk > 0) ? 1.f : 0.f;
            e0[k] = mk * __expf(a0);
            e1[k] = mk * __expf(a1);
            s0 += e0[k];
            s1 += e1[k];
        }
    }

    // ---- denominators over classes (both rows at once) ----
    #pragma unroll
    for (int o = 32; o; o >>= 1) {
        s0 += __shfl_down(s0, o);
        s1 += __shfl_down(s1, o);
    }
    if (lane == 0) { wred[wid] = s0; wred2[wid] = s1; }
    __syncthreads();
    if (t == 0) {
        float z0 = 0.f, z1 = 0.f;
        #pragma unroll
        for (int i = 0; i < 16; ++i) { z0 += wred[i]; z1 += wred2[i]; }
        bc0 = z0; bc1 = z1;
    }
    __syncthreads();
    float inv0 = 1.0f / (bc0 + EPSF);
    float inv1 = 1.0f / (bc1 + EPSF);

    // ---- loss partials ----
    float p1 = 0.f, p2 = 0.f;
    if (t < 250) {
        int c0b = 4 * t;
        float4 sp0 = *(const float4*)&soft[(size_t)sr0 * C_SZ + c0b];
        float4 sp1 = *(const float4*)&soft[(size_t)sr1 * C_SZ + c0b];
        #pragma unroll
        for (int k = 0; k < 4; ++k) {
            float w0 = (k == 0) ? sp0.x : (k == 1) ? sp0.y : (k == 2) ? sp0.z : sp0.w;
            float w1 = (k == 0) ? sp1.x : (k == 1) ? sp1.y : (k == 2) ? sp1.z : sp1.w;
            float lp0 = __logf(e0[k] * inv0 + EPSF);
            float lp1 = __logf(e1[k] * inv1 + EPSF);
            p2 -= w0 * lp0 + w1 * lp1;
            if (c0b + k == tgt0) p1 -= lp0;
            if (c0b + k == tgt1) p1 -= lp1;
        }
    }
    #pragma unroll
    for (int o = 32; o; o >>= 1) {
        p1 += __shfl_down(p1, o);
        p2 += __shfl_down(p2, o);
    }
    __syncthreads();
    if (lane == 0) { wred[wid] = p1; wred2[wid] = p2; }
    __syncthreads();
    if (t == 0) {
        float z1 = 0.f, z2 = 0.f;
        #pragma unroll
        for (int i = 0; i < 16; ++i) { z1 += wred[i]; z2 += wred2[i]; }
        atomicAdd(&acc[0], z1);
        atomicAdd(&acc[1], z2);
        __threadfence();
        int done = atomicAdd(lcnt, 1);
        if (done == (int)gridDim.x - 1) {
            float l1 = atomicAdd(&acc[0], 0.f) / (float)B_SZ;
            float l2 = atomicAdd(&acc[1], 0.f) / (float)B_SZ;
            out[0] = (cur_epoch[0] == 0) ? l1 : 0.5f * (l1 + l2);
        }
    }
}

extern "C" void kernel_launch(void* const* d_in, const int* in_sizes, int n_in,
                              void* d_out, int out_size, void* d_ws, size_t ws_size,
                              hipStream_t stream) {
    const float* feat     = (const float*)d_in[0];
    const float* features = (const float*)d_in[1];
    const float* soft     = (const float*)d_in[2];
    const int* indexes    = (const int*)d_in[3];
    const int* labels     = (const int*)d_in[4];
    const int* bil        = (const int*)d_in[5];
    const int* cur_epoch  = (const int*)d_in[6];

    char* ws = (char*)d_ws;
    unsigned short* fct = (unsigned short*)(ws + OFF_FCT);
    int* nums    = (int*)(ws + OFF_NUMS);
    float* acc   = (float*)(ws + OFF_ACC);
    int* lcnt    = (int*)(ws + OFF_LCNT);

    k_csum<<<NBLK_CSUM, 1024, 0, stream>>>(features, labels, fct, nums, acc, lcnt);
    k_loss<<<B_SZ / 2, 1024, 0, stream>>>(feat, fct, nums, soft, indexes, labels,
                                          bil, cur_epoch, acc, lcnt, (float*)d_out);
}